// Round 2
// baseline (2819.634 us; speedup 1.0000x reference)
//
#include <hip/hip_runtime.h>
#include <stdint.h>

typedef unsigned short u16;
typedef __bf16 bf16x8 __attribute__((ext_vector_type(8)));
typedef float f32x4 __attribute__((ext_vector_type(4)));

#define N_NODES 50000
#define N_PAD   50048      // 391 * 128
#define NUM_E   800000
#define FDIM    256
#define NREL    8

__device__ __forceinline__ u16 f2bf(float f) {
  uint32_t u = __float_as_uint(f);
  u += 0x7FFFu + ((u >> 16) & 1u);   // RNE
  return (u16)(u >> 16);
}
__device__ __forceinline__ float bf2f(u16 h) {
  return __uint_as_float(((uint32_t)h) << 16);
}

// async global->LDS, 16B per lane; LDS dest = wave-uniform base + lane*16
__device__ __forceinline__ void gload_lds16(const void* g, void* l) {
  __builtin_amdgcn_global_load_lds(
      (__attribute__((address_space(1))) uint32_t*)(void*)(uintptr_t)g,
      (__attribute__((address_space(3))) uint32_t*)(uintptr_t)l,
      16, 0, 0);
}

// ---- prep: feat f32 -> bf16, rows >= N_NODES zero-padded ----
__global__ __launch_bounds__(256) void feat_conv(const float* __restrict__ feat,
                                                 u16* __restrict__ fb) {
  int idx = blockIdx.x * 256 + threadIdx.x;       // one thread = 4 elems
  if (idx >= N_PAD * (FDIM / 4)) return;
  int row = idx >> 6;
  int q = (idx & 63) * 4;
  float4 v = make_float4(0.f, 0.f, 0.f, 0.f);
  if (row < N_NODES) v = *reinterpret_cast<const float4*>(feat + (size_t)row * FDIM + q);
  ushort4 h;
  h.x = f2bf(v.x); h.y = f2bf(v.y); h.z = f2bf(v.z); h.w = f2bf(v.w);
  *reinterpret_cast<ushort4*>(fb + (size_t)row * FDIM + q) = h;
}

// ---- prep: W_t[r][o][i] = sum_b w_comp[r][b]*weight[b][i][o] (bf16),
//            lwt[o][i] = loop_weight[i][o] (bf16) ----
__global__ __launch_bounds__(256) void wt_conv(const float* __restrict__ weight,
                                               const float* __restrict__ w_comp,
                                               const float* __restrict__ loop_w,
                                               u16* __restrict__ Wt,
                                               u16* __restrict__ lwt) {
  int idx = blockIdx.x * 256 + threadIdx.x;
  if (idx < NREL * 65536) {
    int r = idx >> 16, rem = idx & 65535;
    int o = rem >> 8, i = rem & 255;
    float s = 0.f;
#pragma unroll
    for (int b = 0; b < 4; ++b)
      s += w_comp[r * 4 + b] * weight[b * 65536 + i * 256 + o];
    Wt[idx] = f2bf(s);                       // layout r*65536 + o*256 + i
  } else if (idx < (NREL + 1) * 65536) {
    int j = idx - NREL * 65536;
    int o = j >> 8, i = j & 255;
    lwt[j] = f2bf(loop_w[i * 256 + o]);
  }
}

// ---- GEMM: C[m][o] = sum_i A[m][i] * B[i][o], A bf16 [N_PAD][256] row-major,
//      Bt bf16 [256(o)][256(i)] (i.e. B^T). MODE 0: write Hr bf16 (stride 2048,
//      col offset rel*256). MODE 1: write f32 out + bias. ----
template <int MODE>
__global__ __launch_bounds__(256) void gemm_k(const u16* __restrict__ A,
                                              const u16* __restrict__ Bt,
                                              u16* __restrict__ Hr,
                                              float* __restrict__ out,
                                              const float* __restrict__ bias) {
  __shared__ __align__(16) u16 As[128 * 64];
  __shared__ __align__(16) u16 Bs[128 * 64];
  const int tid = threadIdx.x;
  const int lane = tid & 63;
  const int w = tid >> 6;
  const int wm = w >> 1, wn = w & 1;
  const int ntile = blockIdx.x;
  const int mtile = blockIdx.y;
  const int rel = blockIdx.z;

  const u16* Ag = A + (size_t)mtile * 128 * 256;
  const u16* Bg = Bt + (size_t)rel * 65536 + (size_t)ntile * 128 * 256;

  f32x4 acc[4][4] = {};

  for (int k0 = 0; k0 < 256; k0 += 64) {
#pragma unroll
    for (int it = 0; it < 4; ++it) {
      const int idx = (it * 4 + w) * 64 + lane;      // 0..1023 lane-loads
      const int row = idx >> 3, c8 = idx & 7;
      const int goff = row * 256 + k0 + c8 * 8;
      gload_lds16(Ag + goff, &As[(it * 4 + w) * 512]);
      gload_lds16(Bg + goff, &Bs[(it * 4 + w) * 512]);
    }
    __syncthreads();   // compiler emits vmcnt(0) before s_barrier
#pragma unroll
    for (int kk = 0; kk < 2; ++kk) {
      const int kb = kk * 32 + (lane >> 4) * 8;
      bf16x8 a[4], b[4];
#pragma unroll
      for (int mf = 0; mf < 4; ++mf)
        a[mf] = *reinterpret_cast<const bf16x8*>(&As[(wm * 64 + mf * 16 + (lane & 15)) * 64 + kb]);
#pragma unroll
      for (int nf = 0; nf < 4; ++nf)
        b[nf] = *reinterpret_cast<const bf16x8*>(&Bs[(wn * 64 + nf * 16 + (lane & 15)) * 64 + kb]);
#pragma unroll
      for (int mf = 0; mf < 4; ++mf)
#pragma unroll
        for (int nf = 0; nf < 4; ++nf)
          // swapped operands: D = (A*B)^T, so D row=o (lane-sequential via reg),
          // D col=m (lane&15) -> vectorized stores along o
          acc[mf][nf] = __builtin_amdgcn_mfma_f32_16x16x32_bf16(b[nf], a[mf], acc[mf][nf], 0, 0, 0);
    }
    __syncthreads();
  }

  // epilogue: per (mf,nf): lane holds 4 consecutive o for one m
#pragma unroll
  for (int mf = 0; mf < 4; ++mf) {
    const int m = mtile * 128 + wm * 64 + mf * 16 + (lane & 15);
    if (m >= N_NODES) continue;
#pragma unroll
    for (int nf = 0; nf < 4; ++nf) {
      const int o0 = ntile * 128 + wn * 64 + nf * 16 + ((lane >> 4) << 2);
      if (MODE == 0) {
        ushort4 h;
        h.x = f2bf(acc[mf][nf][0]);
        h.y = f2bf(acc[mf][nf][1]);
        h.z = f2bf(acc[mf][nf][2]);
        h.w = f2bf(acc[mf][nf][3]);
        *reinterpret_cast<ushort4*>(Hr + (size_t)m * (NREL * 256) + rel * 256 + o0) = h;
      } else {
        const float4 bv = *reinterpret_cast<const float4*>(bias + o0);
        float4 v;
        v.x = acc[mf][nf][0] + bv.x;
        v.y = acc[mf][nf][1] + bv.y;
        v.z = acc[mf][nf][2] + bv.z;
        v.w = acc[mf][nf][3] + bv.w;
        *reinterpret_cast<float4*>(out + (size_t)m * 256 + o0) = v;
      }
    }
  }
}

// ---- per-edge: out[dst] += Hr[src, etype] * norm, one wave per edge ----
__global__ __launch_bounds__(256) void edge_scatter(const u16* __restrict__ Hr,
                                                    const float* __restrict__ norm,
                                                    const int* __restrict__ src,
                                                    const int* __restrict__ dst,
                                                    const int* __restrict__ et,
                                                    float* __restrict__ out) {
  const int e = blockIdx.x * 4 + (threadIdx.x >> 6);
  if (e >= NUM_E) return;
  const int lane = threadIdx.x & 63;
  const int s = src[e], d = dst[e], r = et[e];
  const float nm = norm[e];
  const ushort4 hv = *reinterpret_cast<const ushort4*>(
      Hr + ((size_t)s * NREL + r) * 256 + lane * 4);
  float* op = out + (size_t)d * 256 + lane * 4;
  unsafeAtomicAdd(op + 0, bf2f(hv.x) * nm);
  unsafeAtomicAdd(op + 1, bf2f(hv.y) * nm);
  unsafeAtomicAdd(op + 2, bf2f(hv.z) * nm);
  unsafeAtomicAdd(op + 3, bf2f(hv.w) * nm);
}

__global__ __launch_bounds__(256) void relu_k(float* __restrict__ outp) {
  const int i = blockIdx.x * 256 + threadIdx.x;
  float4* out4 = reinterpret_cast<float4*>(outp);
  float4 v = out4[i];
  v.x = fmaxf(v.x, 0.f);
  v.y = fmaxf(v.y, 0.f);
  v.z = fmaxf(v.z, 0.f);
  v.w = fmaxf(v.w, 0.f);
  out4[i] = v;
}

extern "C" void kernel_launch(void* const* d_in, const int* in_sizes, int n_in,
                              void* d_out, int out_size, void* d_ws, size_t ws_size,
                              hipStream_t stream) {
  (void)in_sizes; (void)n_in; (void)out_size; (void)ws_size;
  const float* feat   = (const float*)d_in[0];
  const float* weight = (const float*)d_in[1];
  const float* w_comp = (const float*)d_in[2];
  const float* loop_w = (const float*)d_in[3];
  const float* h_bias = (const float*)d_in[4];
  const float* norm   = (const float*)d_in[5];
  const int*   src    = (const int*)d_in[6];
  const int*   dst    = (const int*)d_in[7];
  const int*   et     = (const int*)d_in[8];
  float* out = (float*)d_out;

  char* ws = (char*)d_ws;
  u16* feat_bf = (u16*)(ws);                         // 50048*256*2      = 25,624,576
  u16* Wt      = (u16*)(ws + 25624576);              // 8*256*256*2      =  1,048,576
  u16* lwt     = (u16*)(ws + 26673152);              // 256*256*2        =    131,072
  u16* Hr      = (u16*)(ws + 26804224);              // 50000*2048*2     = 204,800,000

  feat_conv<<<N_PAD / 4, 256, 0, stream>>>(feat, feat_bf);
  wt_conv<<<(NREL + 1) * 65536 / 256, 256, 0, stream>>>(weight, w_comp, loop_w, Wt, lwt);
  gemm_k<0><<<dim3(2, N_PAD / 128, NREL), 256, 0, stream>>>(feat_bf, Wt, Hr, nullptr, nullptr);
  gemm_k<1><<<dim3(2, N_PAD / 128, 1), 256, 0, stream>>>(feat_bf, lwt, nullptr, out, h_bias);
  edge_scatter<<<NUM_E / 4, 256, 0, stream>>>(Hr, norm, src, dst, et, out);
  relu_k<<<N_NODES * 256 / 4 / 256, 256, 0, stream>>>(out);
}

// Round 3
// 456.719 us; speedup vs baseline: 6.1737x; 6.1737x over previous
//
#include <hip/hip_runtime.h>
#include <stdint.h>

typedef unsigned short u16;
typedef __bf16 bf16x8 __attribute__((ext_vector_type(8)));
typedef float f32x4 __attribute__((ext_vector_type(4)));

#define N_NODES 50000
#define N_PAD   50048      // 391 * 128
#define NUM_E   800000
#define FDIM    256
#define NREL    8

__device__ __forceinline__ u16 f2bf(float f) {
  uint32_t u = __float_as_uint(f);
  u += 0x7FFFu + ((u >> 16) & 1u);   // RNE
  return (u16)(u >> 16);
}
__device__ __forceinline__ float bf2f(u16 h) {
  return __uint_as_float(((uint32_t)h) << 16);
}

// async global->LDS, 16B per lane; LDS dest = wave-uniform base + lane*16
__device__ __forceinline__ void gload_lds16(const void* g, void* l) {
  __builtin_amdgcn_global_load_lds(
      (__attribute__((address_space(1))) uint32_t*)(void*)(uintptr_t)g,
      (__attribute__((address_space(3))) uint32_t*)(uintptr_t)l,
      16, 0, 0);
}

// ---- prep: feat f32 -> bf16, rows >= N_NODES zero-padded ----
__global__ __launch_bounds__(256) void feat_conv(const float* __restrict__ feat,
                                                 u16* __restrict__ fb) {
  int idx = blockIdx.x * 256 + threadIdx.x;       // one thread = 4 elems
  if (idx >= N_PAD * (FDIM / 4)) return;
  int row = idx >> 6;
  int q = (idx & 63) * 4;
  float4 v = make_float4(0.f, 0.f, 0.f, 0.f);
  if (row < N_NODES) v = *reinterpret_cast<const float4*>(feat + (size_t)row * FDIM + q);
  ushort4 h;
  h.x = f2bf(v.x); h.y = f2bf(v.y); h.z = f2bf(v.z); h.w = f2bf(v.w);
  *reinterpret_cast<ushort4*>(fb + (size_t)row * FDIM + q) = h;
}

// ---- prep: W_t[r][o][i] = sum_b w_comp[r][b]*weight[b][i][o] (bf16),
//            lwt[o][i] = loop_weight[i][o] (bf16) ----
__global__ __launch_bounds__(256) void wt_conv(const float* __restrict__ weight,
                                               const float* __restrict__ w_comp,
                                               const float* __restrict__ loop_w,
                                               u16* __restrict__ Wt,
                                               u16* __restrict__ lwt) {
  int idx = blockIdx.x * 256 + threadIdx.x;
  if (idx < NREL * 65536) {
    int r = idx >> 16, rem = idx & 65535;
    int o = rem >> 8, i = rem & 255;
    float s = 0.f;
#pragma unroll
    for (int b = 0; b < 4; ++b)
      s += w_comp[r * 4 + b] * weight[b * 65536 + i * 256 + o];
    Wt[idx] = f2bf(s);                       // layout r*65536 + o*256 + i
  } else if (idx < (NREL + 1) * 65536) {
    int j = idx - NREL * 65536;
    int o = j >> 8, i = j & 255;
    lwt[j] = f2bf(loop_w[i * 256 + o]);
  }
}

// ---- GEMM: C[m][o] = sum_i A[m][i] * B[i][o] (m97-style 128x128 tile) ----
template <int MODE>
__global__ __launch_bounds__(256) void gemm_k(const u16* __restrict__ A,
                                              const u16* __restrict__ Bt,
                                              u16* __restrict__ Hr,
                                              float* __restrict__ out,
                                              const float* __restrict__ bias) {
  __shared__ __align__(16) u16 As[128 * 64];
  __shared__ __align__(16) u16 Bs[128 * 64];
  const int tid = threadIdx.x;
  const int lane = tid & 63;
  const int w = tid >> 6;
  const int wm = w >> 1, wn = w & 1;
  const int ntile = blockIdx.x;
  const int mtile = blockIdx.y;
  const int rel = blockIdx.z;

  const u16* Ag = A + (size_t)mtile * 128 * 256;
  const u16* Bg = Bt + (size_t)rel * 65536 + (size_t)ntile * 128 * 256;

  f32x4 acc[4][4] = {};

  for (int k0 = 0; k0 < 256; k0 += 64) {
#pragma unroll
    for (int it = 0; it < 4; ++it) {
      const int idx = (it * 4 + w) * 64 + lane;      // 0..1023 lane-loads
      const int row = idx >> 3, c8 = idx & 7;
      const int goff = row * 256 + k0 + c8 * 8;
      gload_lds16(Ag + goff, &As[(it * 4 + w) * 512]);
      gload_lds16(Bg + goff, &Bs[(it * 4 + w) * 512]);
    }
    __syncthreads();
#pragma unroll
    for (int kk = 0; kk < 2; ++kk) {
      const int kb = kk * 32 + (lane >> 4) * 8;
      bf16x8 a[4], b[4];
#pragma unroll
      for (int mf = 0; mf < 4; ++mf)
        a[mf] = *reinterpret_cast<const bf16x8*>(&As[(wm * 64 + mf * 16 + (lane & 15)) * 64 + kb]);
#pragma unroll
      for (int nf = 0; nf < 4; ++nf)
        b[nf] = *reinterpret_cast<const bf16x8*>(&Bs[(wn * 64 + nf * 16 + (lane & 15)) * 64 + kb]);
#pragma unroll
      for (int mf = 0; mf < 4; ++mf)
#pragma unroll
        for (int nf = 0; nf < 4; ++nf)
          acc[mf][nf] = __builtin_amdgcn_mfma_f32_16x16x32_bf16(b[nf], a[mf], acc[mf][nf], 0, 0, 0);
    }
    __syncthreads();
  }

#pragma unroll
  for (int mf = 0; mf < 4; ++mf) {
    const int m = mtile * 128 + wm * 64 + mf * 16 + (lane & 15);
    if (m >= N_NODES) continue;
#pragma unroll
    for (int nf = 0; nf < 4; ++nf) {
      const int o0 = ntile * 128 + wn * 64 + nf * 16 + ((lane >> 4) << 2);
      if (MODE == 0) {
        ushort4 h;
        h.x = f2bf(acc[mf][nf][0]);
        h.y = f2bf(acc[mf][nf][1]);
        h.z = f2bf(acc[mf][nf][2]);
        h.w = f2bf(acc[mf][nf][3]);
        *reinterpret_cast<ushort4*>(Hr + (size_t)m * (NREL * 256) + rel * 256 + o0) = h;
      } else {
        const float4 bv = *reinterpret_cast<const float4*>(bias + o0);
        float4 v;
        v.x = acc[mf][nf][0] + bv.x;
        v.y = acc[mf][nf][1] + bv.y;
        v.z = acc[mf][nf][2] + bv.z;
        v.w = acc[mf][nf][3] + bv.w;
        *reinterpret_cast<float4*>(out + (size_t)m * 256 + o0) = v;
      }
    }
  }
}

// ---- CSR build: histogram of dst ----
__global__ __launch_bounds__(256) void zero_counts(int* __restrict__ cnt) {
  int i = blockIdx.x * 256 + threadIdx.x;
  if (i < N_PAD) cnt[i] = 0;
}

__global__ __launch_bounds__(256) void hist_k(const int* __restrict__ dst,
                                              int* __restrict__ cnt) {
  int e = blockIdx.x * 256 + threadIdx.x;
  if (e < NUM_E) atomicAdd(&cnt[dst[e]], 1);
}

// ---- single-block exclusive scan over counts -> rowstart, cursor ----
__global__ __launch_bounds__(1024) void scan_k(const int* __restrict__ cnt,
                                               int* __restrict__ rowstart,
                                               int* __restrict__ cursor) {
  __shared__ int sdata[1024];
  const int tid = threadIdx.x;
  int running = 0;
  for (int base = 0; base < N_NODES; base += 1024) {
    const int i = base + tid;
    const int v = (i < N_NODES) ? cnt[i] : 0;
    sdata[tid] = v;
    __syncthreads();
#pragma unroll
    for (int off = 1; off < 1024; off <<= 1) {
      int t = (tid >= off) ? sdata[tid - off] : 0;
      __syncthreads();
      sdata[tid] += t;
      __syncthreads();
    }
    const int excl = sdata[tid] - v;
    if (i < N_NODES) {
      rowstart[i] = running + excl;
      cursor[i]   = running + excl;
    }
    const int chunk_total = sdata[1023];
    __syncthreads();
    running += chunk_total;
  }
  if (tid == 0) rowstart[N_NODES] = running;   // = NUM_E
}

// ---- bucket: pack (src*8+etype, norm) sorted by dst ----
__global__ __launch_bounds__(256) void bucket_k(const int* __restrict__ src,
                                                const int* __restrict__ dst,
                                                const int* __restrict__ et,
                                                const float* __restrict__ norm,
                                                int* __restrict__ cursor,
                                                int* __restrict__ keys,
                                                float* __restrict__ norms) {
  int e = blockIdx.x * 256 + threadIdx.x;
  if (e >= NUM_E) return;
  const int d = dst[e];
  const int pos = atomicAdd(&cursor[d], 1);
  keys[pos]  = src[e] * NREL + et[e];
  norms[pos] = norm[e];
}

// ---- gather-aggregate: one wave per dst node; fuse self-loop add + ReLU ----
__global__ __launch_bounds__(256) void edge_aggregate(const u16* __restrict__ Hr,
                                                      const int* __restrict__ rowstart,
                                                      const int* __restrict__ keys,
                                                      const float* __restrict__ norms,
                                                      float* __restrict__ out) {
  const int n = blockIdx.x * 4 + (threadIdx.x >> 6);
  if (n >= N_NODES) return;
  const int lane = threadIdx.x & 63;
  const int beg = rowstart[n], end = rowstart[n + 1];

  float4 acc = make_float4(0.f, 0.f, 0.f, 0.f);
  if (beg < end) {
    // 1-ahead software pipeline on the dependent key->row chain
    int k = keys[beg];
    float nm = norms[beg];
    ushort4 h = *reinterpret_cast<const ushort4*>(Hr + (size_t)k * 256 + lane * 4);
    for (int j = beg; j < end; ++j) {
      ushort4 h2; float nm2 = 0.f;
      if (j + 1 < end) {
        const int k2 = keys[j + 1];
        nm2 = norms[j + 1];
        h2 = *reinterpret_cast<const ushort4*>(Hr + (size_t)k2 * 256 + lane * 4);
      }
      acc.x += bf2f(h.x) * nm;
      acc.y += bf2f(h.y) * nm;
      acc.z += bf2f(h.z) * nm;
      acc.w += bf2f(h.w) * nm;
      h = h2; nm = nm2;
    }
  }

  float4* op = reinterpret_cast<float4*>(out + (size_t)n * 256) + lane;
  float4 o = *op;   // self-loop + bias, written by gemm_k<1>
  o.x = fmaxf(o.x + acc.x, 0.f);
  o.y = fmaxf(o.y + acc.y, 0.f);
  o.z = fmaxf(o.z + acc.z, 0.f);
  o.w = fmaxf(o.w + acc.w, 0.f);
  *op = o;
}

extern "C" void kernel_launch(void* const* d_in, const int* in_sizes, int n_in,
                              void* d_out, int out_size, void* d_ws, size_t ws_size,
                              hipStream_t stream) {
  (void)in_sizes; (void)n_in; (void)out_size; (void)ws_size;
  const float* feat   = (const float*)d_in[0];
  const float* weight = (const float*)d_in[1];
  const float* w_comp = (const float*)d_in[2];
  const float* loop_w = (const float*)d_in[3];
  const float* h_bias = (const float*)d_in[4];
  const float* norm   = (const float*)d_in[5];
  const int*   src    = (const int*)d_in[6];
  const int*   dst    = (const int*)d_in[7];
  const int*   et     = (const int*)d_in[8];
  float* out = (float*)d_out;

  char* ws = (char*)d_ws;
  u16*   feat_bf  = (u16*)(ws);                      // 25,624,576
  u16*   Wt       = (u16*)(ws + 25624576);           //  1,048,576
  u16*   lwt      = (u16*)(ws + 26673152);           //    131,072
  u16*   Hr       = (u16*)(ws + 26804224);           // 204,800,000
  int*   counts   = (int*)(ws + 231604224);          //    200,192
  int*   rowstart = (int*)(ws + 231804416);          //    200,192
  int*   cursor   = (int*)(ws + 232004608);          //    200,192
  int*   keys     = (int*)(ws + 232204800);          //  3,200,000
  float* norms    = (float*)(ws + 235404800);        //  3,200,000  (end 238,604,800)

  // CSR build (independent of GEMMs)
  zero_counts<<<(N_PAD + 255) / 256, 256, 0, stream>>>(counts);
  hist_k<<<(NUM_E + 255) / 256, 256, 0, stream>>>(dst, counts);
  scan_k<<<1, 1024, 0, stream>>>(counts, rowstart, cursor);
  bucket_k<<<(NUM_E + 255) / 256, 256, 0, stream>>>(src, dst, et, norm, cursor, keys, norms);

  // dense transforms
  feat_conv<<<N_PAD / 4, 256, 0, stream>>>(feat, feat_bf);
  wt_conv<<<(NREL + 1) * 65536 / 256, 256, 0, stream>>>(weight, w_comp, loop_w, Wt, lwt);
  gemm_k<0><<<dim3(2, N_PAD / 128, NREL), 256, 0, stream>>>(feat_bf, Wt, Hr, nullptr, nullptr);
  gemm_k<1><<<dim3(2, N_PAD / 128, 1), 256, 0, stream>>>(feat_bf, lwt, nullptr, out, h_bias);

  // gather + self-loop + relu
  edge_aggregate<<<(N_NODES + 3) / 4, 256, 0, stream>>>(Hr, rowstart, keys, norms, out);
}

// Round 4
// 330.557 us; speedup vs baseline: 8.5299x; 1.3817x over previous
//
#include <hip/hip_runtime.h>
#include <stdint.h>

typedef unsigned short u16;
typedef __bf16 bf16x8 __attribute__((ext_vector_type(8)));
typedef float f32x4 __attribute__((ext_vector_type(4)));

#define N_NODES 50000
#define N_PAD   50048      // 391 * 128
#define NUM_E   800000
#define FDIM    256
#define NREL    8
#define NSEG    (N_NODES * NREL)       // 400000 (dst,rel) segments
#define NBLK    391                    // ceil(NSEG/1024)

__device__ __forceinline__ u16 f2bf(float f) {
  uint32_t u = __float_as_uint(f);
  u += 0x7FFFu + ((u >> 16) & 1u);   // RNE
  return (u16)(u >> 16);
}
__device__ __forceinline__ float bf2f(u16 h) {
  return __uint_as_float(((uint32_t)h) << 16);
}

// async global->LDS, 16B per lane; LDS dest = wave-uniform base + lane*16
__device__ __forceinline__ void gload_lds16(const void* g, void* l) {
  __builtin_amdgcn_global_load_lds(
      (__attribute__((address_space(1))) uint32_t*)(void*)(uintptr_t)g,
      (__attribute__((address_space(3))) uint32_t*)(uintptr_t)l,
      16, 0, 0);
}

// ---- prep: feat f32 -> bf16, rows >= N_NODES zero-padded ----
__global__ __launch_bounds__(256) void feat_conv(const float* __restrict__ feat,
                                                 u16* __restrict__ fb) {
  int idx = blockIdx.x * 256 + threadIdx.x;       // one thread = 4 elems
  if (idx >= N_PAD * (FDIM / 4)) return;
  int row = idx >> 6;
  int q = (idx & 63) * 4;
  float4 v = make_float4(0.f, 0.f, 0.f, 0.f);
  if (row < N_NODES) v = *reinterpret_cast<const float4*>(feat + (size_t)row * FDIM + q);
  ushort4 h;
  h.x = f2bf(v.x); h.y = f2bf(v.y); h.z = f2bf(v.z); h.w = f2bf(v.w);
  *reinterpret_cast<ushort4*>(fb + (size_t)row * FDIM + q) = h;
}

// ---- prep: W_all[r][o][i]: r<8 = sum_b w_comp[r][b]*weight[b][i][o];
//            r==8 = loop_weight[i][o]  (all bf16, o-major = B^T layout) ----
__global__ __launch_bounds__(256) void wt_conv(const float* __restrict__ weight,
                                               const float* __restrict__ w_comp,
                                               const float* __restrict__ loop_w,
                                               u16* __restrict__ W_all) {
  int idx = blockIdx.x * 256 + threadIdx.x;
  if (idx < NREL * 65536) {
    int r = idx >> 16, rem = idx & 65535;
    int o = rem >> 8, i = rem & 255;
    float s = 0.f;
#pragma unroll
    for (int b = 0; b < 4; ++b)
      s += w_comp[r * 4 + b] * weight[b * 65536 + i * 256 + o];
    W_all[idx] = f2bf(s);
  } else if (idx < (NREL + 1) * 65536) {
    int j = idx - NREL * 65536;
    int o = j >> 8, i = j & 255;
    W_all[idx] = f2bf(loop_w[i * 256 + o]);
  }
}

// ---- CSR build over key = dst*8 + etype ----
__global__ __launch_bounds__(256) void hist_k(const int* __restrict__ dst,
                                              const int* __restrict__ et,
                                              int* __restrict__ cnt) {
  int e = blockIdx.x * 256 + threadIdx.x;
  if (e < NUM_E) atomicAdd(&cnt[dst[e] * NREL + et[e]], 1);
}

// block-level scan (1024/block): rowstart[i] = in-block exclusive prefix
__global__ __launch_bounds__(1024) void scan1(const int* __restrict__ cnt,
                                              int* __restrict__ rowstart,
                                              int* __restrict__ blocksum) {
  __shared__ int wtot[16], woff[16];
  const int tid = threadIdx.x, lane = tid & 63, w = tid >> 6;
  const int i = blockIdx.x * 1024 + tid;
  const int v = (i < NSEG) ? cnt[i] : 0;
  int inc = v;
#pragma unroll
  for (int off = 1; off < 64; off <<= 1) {
    int t = __shfl_up(inc, off);
    if (lane >= off) inc += t;
  }
  if (lane == 63) wtot[w] = inc;
  __syncthreads();
  if (w == 0) {
    int tv = (lane < 16) ? wtot[lane] : 0;
    int tinc = tv;
#pragma unroll
    for (int off = 1; off < 16; off <<= 1) {
      int t = __shfl_up(tinc, off);
      if (lane >= off) tinc += t;
    }
    if (lane < 16) woff[lane] = tinc - tv;
    if (lane == 15) blocksum[blockIdx.x] = tinc;
  }
  __syncthreads();
  if (i < NSEG) rowstart[i] = inc - v + woff[w];
}

// exclusive scan of the 391 block sums (single block)
__global__ __launch_bounds__(512) void scan2(int* __restrict__ blocksum) {
  __shared__ int s[512];
  const int tid = threadIdx.x;
  const int v = (tid < NBLK) ? blocksum[tid] : 0;
  s[tid] = v;
#pragma unroll
  for (int off = 1; off < 512; off <<= 1) {
    __syncthreads();
    int t = (tid >= off) ? s[tid - off] : 0;
    __syncthreads();
    s[tid] += t;
  }
  if (tid < NBLK) blocksum[tid] = s[tid] - v;
}

// add block offsets in place; init cursor; terminator
__global__ __launch_bounds__(1024) void scan3(int* __restrict__ rowstart,
                                              const int* __restrict__ blockoff,
                                              int* __restrict__ cursor) {
  const int i = blockIdx.x * 1024 + threadIdx.x;
  if (i < NSEG) {
    const int v = rowstart[i] + blockoff[i >> 10];
    rowstart[i] = v;
    cursor[i] = v;
  }
  if (i == NSEG) rowstart[NSEG] = NUM_E;
}

// bucket edges into CSR order: store src and norm
__global__ __launch_bounds__(256) void bucket_k(const int* __restrict__ src,
                                                const int* __restrict__ dst,
                                                const int* __restrict__ et,
                                                const float* __restrict__ norm,
                                                int* __restrict__ cursor,
                                                int* __restrict__ keys,
                                                float* __restrict__ norms) {
  int e = blockIdx.x * 256 + threadIdx.x;
  if (e >= NUM_E) return;
  const int pos = atomicAdd(&cursor[dst[e] * NREL + et[e]], 1);
  keys[pos]  = src[e];
  norms[pos] = norm[e];
}

// ---- aggregate features per (dst, rel): T[dst][r][:] = sum norm*feat[src] ----
__global__ __launch_bounds__(256) void agg_T(const u16* __restrict__ feat_bf,
                                             const int* __restrict__ rowstart,
                                             const int* __restrict__ keys,
                                             const float* __restrict__ norms,
                                             u16* __restrict__ T) {
  const int n = blockIdx.x * 4 + (threadIdx.x >> 6);
  if (n >= N_NODES) return;
  const int lane = threadIdx.x & 63;
  int rsv = 0;
  if (lane < 9) rsv = rowstart[n * NREL + lane];
  f32x4 acc[8] = {};
#pragma unroll
  for (int r = 0; r < 8; ++r) {
    const int b = __shfl(rsv, r), e = __shfl(rsv, r + 1);
    for (int base = b; base < e; base += 64) {
      const int m = min(64, e - base);
      int kv = 0; float nv = 0.f;
      if (lane < m) { kv = keys[base + lane]; nv = norms[base + lane]; }
      for (int j = 0; j < m; ++j) {
        const int s = __shfl(kv, j);
        const float nm = __shfl(nv, j);
        const ushort4 h = *reinterpret_cast<const ushort4*>(
            feat_bf + (size_t)s * FDIM + lane * 4);
        acc[r][0] += bf2f(h.x) * nm;
        acc[r][1] += bf2f(h.y) * nm;
        acc[r][2] += bf2f(h.z) * nm;
        acc[r][3] += bf2f(h.w) * nm;
      }
    }
  }
#pragma unroll
  for (int r = 0; r < 8; ++r) {
    ushort4 hh;
    hh.x = f2bf(acc[r][0]);
    hh.y = f2bf(acc[r][1]);
    hh.z = f2bf(acc[r][2]);
    hh.w = f2bf(acc[r][3]);
    *reinterpret_cast<ushort4*>(T + (size_t)n * (NREL * FDIM) + r * FDIM + lane * 4) = hh;
  }
}

// ---- fused GEMM: out[m][o] = relu( sum_{r<8} T[m][r][:]@W_r + feat[m]@lw + bias )
//      BM=128, BN=256 (full width), BK=64, K = 9*256 = 2304, 8 waves ----
__global__ __launch_bounds__(512) void fused_gemm(const u16* __restrict__ T,
                                                  const u16* __restrict__ feat_bf,
                                                  const u16* __restrict__ W_all,
                                                  const float* __restrict__ bias,
                                                  float* __restrict__ out) {
  __shared__ __align__(16) u16 As[128 * 64];   // 16 KB
  __shared__ __align__(16) u16 Bs[256 * 64];   // 32 KB
  const int tid = threadIdx.x;
  const int lane = tid & 63;
  const int w = tid >> 6;          // 0..7
  const int wm = w >> 2, wn = w & 3;
  const int mtile = blockIdx.x;

  f32x4 acc[4][4] = {};

  for (int ks = 0; ks < 36; ++ks) {
    const int r = ks >> 2, kk = ks & 3;
    // stage A: 128x64 from T (r<8) or feat_bf (r==8)
    const u16* Asrc;
    int stride;
    if (r < 8) { Asrc = T + (size_t)mtile * 128 * 2048 + r * 256 + kk * 64; stride = 2048; }
    else       { Asrc = feat_bf + (size_t)mtile * 128 * 256 + kk * 64;      stride = 256; }
#pragma unroll
    for (int it = 0; it < 2; ++it) {
      const int idx = it * 512 + tid;            // 0..1023
      const int row = idx >> 3, c8 = idx & 7;
      gload_lds16(Asrc + (size_t)row * stride + c8 * 8, &As[idx * 8]);
    }
    // stage B: 256x64 from W_all[r]
    const u16* Bsrc = W_all + (size_t)r * 65536 + kk * 64;
#pragma unroll
    for (int it = 0; it < 4; ++it) {
      const int idx = it * 512 + tid;            // 0..2047
      const int row = idx >> 3, c8 = idx & 7;
      gload_lds16(Bsrc + (size_t)row * 256 + c8 * 8, &Bs[idx * 8]);
    }
    __syncthreads();
#pragma unroll
    for (int k2 = 0; k2 < 2; ++k2) {
      const int kb = k2 * 32 + (lane >> 4) * 8;
      bf16x8 a[4], b[4];
#pragma unroll
      for (int mf = 0; mf < 4; ++mf)
        a[mf] = *reinterpret_cast<const bf16x8*>(&As[(wm * 64 + mf * 16 + (lane & 15)) * 64 + kb]);
#pragma unroll
      for (int nf = 0; nf < 4; ++nf)
        b[nf] = *reinterpret_cast<const bf16x8*>(&Bs[(wn * 64 + nf * 16 + (lane & 15)) * 64 + kb]);
#pragma unroll
      for (int mf = 0; mf < 4; ++mf)
#pragma unroll
        for (int nf = 0; nf < 4; ++nf)
          acc[mf][nf] = __builtin_amdgcn_mfma_f32_16x16x32_bf16(b[nf], a[mf], acc[mf][nf], 0, 0, 0);
    }
    __syncthreads();
  }

  // epilogue: out = relu(acc + bias), o lane-sequential -> float4 stores
#pragma unroll
  for (int mf = 0; mf < 4; ++mf) {
    const int m = mtile * 128 + wm * 64 + mf * 16 + (lane & 15);
    if (m >= N_NODES) continue;
#pragma unroll
    for (int nf = 0; nf < 4; ++nf) {
      const int o0 = wn * 64 + nf * 16 + ((lane >> 4) << 2);
      const float4 bv = *reinterpret_cast<const float4*>(bias + o0);
      float4 v;
      v.x = fmaxf(acc[mf][nf][0] + bv.x, 0.f);
      v.y = fmaxf(acc[mf][nf][1] + bv.y, 0.f);
      v.z = fmaxf(acc[mf][nf][2] + bv.z, 0.f);
      v.w = fmaxf(acc[mf][nf][3] + bv.w, 0.f);
      *reinterpret_cast<float4*>(out + (size_t)m * 256 + o0) = v;
    }
  }
}

extern "C" void kernel_launch(void* const* d_in, const int* in_sizes, int n_in,
                              void* d_out, int out_size, void* d_ws, size_t ws_size,
                              hipStream_t stream) {
  (void)in_sizes; (void)n_in; (void)out_size; (void)ws_size;
  const float* feat   = (const float*)d_in[0];
  const float* weight = (const float*)d_in[1];
  const float* w_comp = (const float*)d_in[2];
  const float* loop_w = (const float*)d_in[3];
  const float* h_bias = (const float*)d_in[4];
  const float* norm   = (const float*)d_in[5];
  const int*   src    = (const int*)d_in[6];
  const int*   dst    = (const int*)d_in[7];
  const int*   et     = (const int*)d_in[8];
  float* out = (float*)d_out;

  char* ws = (char*)d_ws;
  u16*   feat_bf  = (u16*)(ws);                      // 25,624,576
  u16*   W_all    = (u16*)(ws + 25624576);           //  1,179,648
  u16*   T        = (u16*)(ws + 26804224);           // 205,000,704 (N_PAD*2048*2)
  int*   counts   = (int*)(ws + 231804928);          //  1,600,000
  int*   rowstart = (int*)(ws + 233404928);          //  1,600,256 (NSEG+1, padded)
  int*   cursor   = (int*)(ws + 235005184);          //  1,600,000
  int*   keys     = (int*)(ws + 236605184);          //  3,200,000
  float* norms    = (float*)(ws + 239805184);        //  3,200,000
  int*   blocksum = (int*)(ws + 243005184);          //      1,564

  // CSR build over (dst, rel)
  hipMemsetAsync(counts, 0, NSEG * sizeof(int), stream);
  hist_k<<<(NUM_E + 255) / 256, 256, 0, stream>>>(dst, et, counts);
  scan1<<<NBLK, 1024, 0, stream>>>(counts, rowstart, blocksum);
  scan2<<<1, 512, 0, stream>>>(blocksum);
  scan3<<<NBLK + 1, 1024, 0, stream>>>(rowstart, blocksum, cursor);
  bucket_k<<<(NUM_E + 255) / 256, 256, 0, stream>>>(src, dst, et, norm, cursor, keys, norms);

  // dense prep
  feat_conv<<<N_PAD / 4, 256, 0, stream>>>(feat, feat_bf);
  wt_conv<<<(NREL + 1) * 65536 / 256, 256, 0, stream>>>(weight, w_comp, loop_w, W_all);

  // aggregate feats per (dst, rel)
  agg_T<<<(N_NODES + 3) / 4, 256, 0, stream>>>(feat_bf, rowstart, keys, norms, T);

  // one fused GEMM: K = 8 relations + self-loop; bias + relu fused
  fused_gemm<<<N_PAD / 128, 512, 0, stream>>>(T, feat_bf, W_all, h_bias, out);
}